// Round 7
// baseline (185.463 us; speedup 1.0000x reference)
//
#include <hip/hip_runtime.h>

// SNN excitatory layer only (inhibitory layer never affects the returned
// spikes — the scan discards its carry).
//
// R6 changes vs R5:
//  - diagnosis: ~1400 of 1785 cy/step are memory stalls; every wave pulls
//    the same 8 KB x-row through per-CU L1 (64 KB/step/CU at ~64 B/cy).
//  - fix: block-level LDS staging of x (LDS = 256 B/cy/CU, bypasses L1),
//    with a 4-step window: 8-row LDS ring (64 KB), loads for rows t+4..t+7
//    issued at window top into registers, ds_write at window END (4 steps
//    of slack), ONE __syncthreads per 4 steps (32 barriers vs 128).
//  - ds_reads issue at step top; latency hides under scalar LIF + the
//    previous step's reduce tail.
//  - everything else identical to R5 (DPP reduce, clamp-fma STDP, spike
//    decided before the dot, reduce last) -> bit-exact spikes.

constexpr int T_STEPS = 128;
constexpr int N_IN    = 2048;
constexpr int N_EXC   = 2048;

// t_pre[t][j]: trace AFTER the step-t update (what stdp_step's dw uses).
__global__ __launch_bounds__(256)
void tp_precompute_kernel(const float* __restrict__ x, float* __restrict__ tp_ws) {
    const int j = blockIdx.x * blockDim.x + threadIdx.x;
    float tp = 0.f;
    #pragma unroll 4
    for (int t = 0; t < T_STEPS; ++t) {
        tp = fmaf(0.05f, x[t * N_IN + j] - tp, tp);
        tp_ws[t * N_IN + j] = tp;
    }
}

template <int CTRL, int RM>
__device__ __forceinline__ float dpp_add(float x) {
    int t = __builtin_amdgcn_update_dpp(0, __builtin_bit_cast(int, x),
                                        CTRL, RM, 0xF, true);
    return x + __builtin_bit_cast(float, t);
}

// Sum across 64 lanes; returns wave-uniform scalar (readlane 63 -> SGPR).
__device__ __forceinline__ float wave_sum64(float x) {
    x = dpp_add<0x111, 0xF>(x);   // row_shr:1
    x = dpp_add<0x112, 0xF>(x);   // row_shr:2
    x = dpp_add<0x114, 0xF>(x);   // row_shr:4
    x = dpp_add<0x118, 0xF>(x);   // row_shr:8
    x = dpp_add<0x142, 0xA>(x);   // row_bcast:15 -> rows 1,3
    x = dpp_add<0x143, 0xC>(x);   // row_bcast:31 -> rows 2,3
    return __builtin_bit_cast(float,
        __builtin_amdgcn_readlane(__builtin_bit_cast(int, x), 63));
}

__device__ __forceinline__ float clamp01(float x) {
    return __builtin_amdgcn_fmed3f(x, 0.f, 1.f);   // folds to clamp bit
}

__global__ __launch_bounds__(256, 2)
void snn_exc_kernel(const float* __restrict__ x,     // [T, N_IN]
                    const float* __restrict__ w0,    // [N_EXC, N_IN]
                    const float* __restrict__ tp_ws, // [T, N_IN]
                    float* __restrict__ out)         // [T, N_EXC]
{
    __shared__ __align__(16) float xs[8][N_IN];      // 64 KiB, 8-row ring

    const int tid  = threadIdx.x;
    const int lane = tid & 63;
    const int wid  = tid >> 6;
    const int row  = blockIdx.x * 4 + wid;

    // lane l owns columns j = m*256 + l*4 + {0..3}, m = 0..7
    float w[32];
    {
        const float4* wrow = reinterpret_cast<const float4*>(w0 + (size_t)row * N_IN);
        #pragma unroll
        for (int m = 0; m < 8; ++m) {
            float4 t4 = wrow[m * 64 + lane];
            w[4*m+0] = t4.x; w[4*m+1] = t4.y; w[4*m+2] = t4.z; w[4*m+3] = t4.w;
        }
    }

    // this wave stages columns [wid*512, wid*512+512) of each x row,
    // as two 1 KiB chunks; lane l covers floats [.. + l*4, +4).
    const size_t stage_off = (size_t)wid * 512 + (size_t)lane * 4;
    const float4* tpb = reinterpret_cast<const float4*>(tp_ws) + lane;
    float* outp = out + row;

    float4 pr[8];   // pending 4 rows x 2 chunks, live across one window
    #pragma unroll
    for (int j = 0; j < 4; ++j) {       // prologue: load rows 0..3
        const float* src = x + (size_t)j * N_IN + stage_off;
        pr[2*j+0] = *reinterpret_cast<const float4*>(src);
        pr[2*j+1] = *reinterpret_cast<const float4*>(src + 256);
    }

    float v = 0.f, syn = 0.f, rho = 0.f, tpost = 0.f;

    auto step = [&](int t) {
        // ---- (1) x fragments from LDS (issued first; latency hides under
        //          the scalar LIF + previous reduce tail) ----
        float4 xq[8];
        {
            const float4* xl = reinterpret_cast<const float4*>(xs[t & 7]);
            #pragma unroll
            for (int m = 0; m < 8; ++m) xq[m] = xl[m * 64 + lane];
        }

        // ---- (2) scalar LIF: spike known BEFORE the dot (v_dec uses the
        //          OLD synaptic current) ----
        const float v_dec = fmaf(0.1f, syn - v, v);
        const bool refrac = (rho > 0.f);
        const bool spike  = (v_dec > 1.0f) && !refrac;
        v   = (spike || refrac) ? 0.f : v_dec;
        rho = spike ? 5.0f : fmaxf(rho - 1.0f, 0.f);
        const float zf = spike ? 1.f : 0.f;
        tpost = fmaf(0.05f, zf - tpost, tpost);
        const float c2 = 1e-3f * tpost;
        if (lane == 0) *outp = zf;
        outp += N_EXC;

        // ---- (3) early t_pre loads on spike steps ----
        float4 tq[8];
        if (spike) {
            const float4* tq4 = tpb + (size_t)t * (N_IN / 4);
            #pragma unroll
            for (int m = 0; m < 8; ++m) tq[m] = tq4[m * 64];
        }

        // ---- (4) dot product over PRE-update w ----
        float a0 = 0.f, a1 = 0.f, a2 = 0.f, a3 = 0.f;
        #pragma unroll
        for (int m = 0; m < 8; ++m) {
            a0 = fmaf(xq[m].x, w[4*m+0], a0);
            a1 = fmaf(xq[m].y, w[4*m+1], a1);
            a2 = fmaf(xq[m].z, w[4*m+2], a2);
            a3 = fmaf(xq[m].w, w[4*m+3], a3);
        }

        // ---- (5) STDP update: 1 clamp-fma/elem non-spike ----
        if (spike) {
            #pragma unroll
            for (int m = 0; m < 8; ++m) {
                w[4*m+0] = clamp01(fmaf(1e-3f, tq[m].x, fmaf(-c2, xq[m].x, w[4*m+0])));
                w[4*m+1] = clamp01(fmaf(1e-3f, tq[m].y, fmaf(-c2, xq[m].y, w[4*m+1])));
                w[4*m+2] = clamp01(fmaf(1e-3f, tq[m].z, fmaf(-c2, xq[m].z, w[4*m+2])));
                w[4*m+3] = clamp01(fmaf(1e-3f, tq[m].w, fmaf(-c2, xq[m].w, w[4*m+3])));
            }
        } else {
            #pragma unroll
            for (int m = 0; m < 8; ++m) {
                w[4*m+0] = clamp01(fmaf(-c2, xq[m].x, w[4*m+0]));
                w[4*m+1] = clamp01(fmaf(-c2, xq[m].y, w[4*m+1]));
                w[4*m+2] = clamp01(fmaf(-c2, xq[m].z, w[4*m+2]));
                w[4*m+3] = clamp01(fmaf(-c2, xq[m].w, w[4*m+3]));
            }
        }

        // ---- (6) reduce LAST: consumed by step t+1's syn update ----
        syn = fmaf(0.8f, syn, wave_sum64((a0 + a1) + (a2 + a3)));
    };

    for (int tb = 0; tb < T_STEPS; tb += 4) {
        // publish pending rows tb..tb+3 (loaded last window; 4 steps of
        // slack -> no vmcnt stall). Slots were last read 2 windows ago.
        #pragma unroll
        for (int j = 0; j < 4; ++j) {
            float* dst = &xs[(tb + j) & 7][0] + stage_off;
            *reinterpret_cast<float4*>(dst)       = pr[2*j+0];
            *reinterpret_cast<float4*>(dst + 256) = pr[2*j+1];
        }
        __syncthreads();
        if (tb + 4 < T_STEPS) {     // issue loads for rows tb+4..tb+7
            #pragma unroll
            for (int j = 0; j < 4; ++j) {
                const float* src = x + (size_t)(tb + 4 + j) * N_IN + stage_off;
                pr[2*j+0] = *reinterpret_cast<const float4*>(src);
                pr[2*j+1] = *reinterpret_cast<const float4*>(src + 256);
            }
        }
        step(tb + 0);
        step(tb + 1);
        step(tb + 2);
        step(tb + 3);
    }
}

extern "C" void kernel_launch(void* const* d_in, const int* in_sizes, int n_in,
                              void* d_out, int out_size, void* d_ws, size_t ws_size,
                              hipStream_t stream) {
    const float* x  = (const float*)d_in[0];   // exc_currents [128, 2048] f32
    const float* w0 = (const float*)d_in[1];   // w_exc [2048, 2048] f32
    // d_in[2] (w_inh) unused: inhibitory layer does not affect the output
    float* out = (float*)d_out;                // spikes [128, 2048] f32

    float* tp_ws = (float*)d_ws;               // 1 MiB, ws_size is ample
    tp_precompute_kernel<<<N_IN / 256, 256, 0, stream>>>(x, tp_ws);

    dim3 grid(N_EXC / 4);                      // 512 blocks, 2 blocks/CU
    dim3 block(256);                           // 4 waves = 4 neurons
    snn_exc_kernel<<<grid, block, 0, stream>>>(x, w0, tp_ws, out);
}

// Round 8
// 93.331 us; speedup vs baseline: 1.9872x; 1.9872x over previous
//
#include <hip/hip_runtime.h>

// SNN excitatory layer only (inhibitory layer never affects the returned
// spikes — the scan discards its carry).
//
// R7 = R5 + minimal-register LDS staging of x (R6 retried without spills):
//  - R6 post-mortem: 4-row staging window (pr[8]=32 VGPRs) caused scratch
//    spills (WRITE_SIZE 2MB -> 155MB, VALUBusy 29%). The staging idea was
//    never actually tested. Here: double-buffer ONE row ahead (pr = 8 VGPRs,
//    LDS = 2 x 8 KB), one barrier per step.
//  - step layout: ds_read row t  ->  ds_write row t+1  ->  __syncthreads
//    (drains lgkm: own reads done before signaling -> one barrier suffices
//    for both buffers)  ->  global-load row t+2 (full step of slack)  ->
//    LIF / dot / STDP / DPP-reduce (all R5-identical -> bit-exact).
//  - cuts per-CU x traffic through L1/L2 4x; x reads become conflict-free
//    ds_read_b128 served by LDS at 256 B/cy/CU.

constexpr int T_STEPS = 128;
constexpr int N_IN    = 2048;
constexpr int N_EXC   = 2048;

// t_pre[t][j]: trace AFTER the step-t update (what stdp_step's dw uses).
__global__ __launch_bounds__(256)
void tp_precompute_kernel(const float* __restrict__ x, float* __restrict__ tp_ws) {
    const int j = blockIdx.x * blockDim.x + threadIdx.x;
    float tp = 0.f;
    #pragma unroll 4
    for (int t = 0; t < T_STEPS; ++t) {
        tp = fmaf(0.05f, x[t * N_IN + j] - tp, tp);
        tp_ws[t * N_IN + j] = tp;
    }
}

template <int CTRL, int RM>
__device__ __forceinline__ float dpp_add(float x) {
    int t = __builtin_amdgcn_update_dpp(0, __builtin_bit_cast(int, x),
                                        CTRL, RM, 0xF, true);
    return x + __builtin_bit_cast(float, t);
}

// Sum across 64 lanes; returns wave-uniform scalar (readlane 63 -> SGPR).
__device__ __forceinline__ float wave_sum64(float x) {
    x = dpp_add<0x111, 0xF>(x);   // row_shr:1
    x = dpp_add<0x112, 0xF>(x);   // row_shr:2
    x = dpp_add<0x114, 0xF>(x);   // row_shr:4
    x = dpp_add<0x118, 0xF>(x);   // row_shr:8
    x = dpp_add<0x142, 0xA>(x);   // row_bcast:15 -> rows 1,3
    x = dpp_add<0x143, 0xC>(x);   // row_bcast:31 -> rows 2,3
    return __builtin_bit_cast(float,
        __builtin_amdgcn_readlane(__builtin_bit_cast(int, x), 63));
}

__device__ __forceinline__ float clamp01(float x) {
    return __builtin_amdgcn_fmed3f(x, 0.f, 1.f);   // folds to clamp bit
}

__global__ __launch_bounds__(256, 2)
void snn_exc_kernel(const float* __restrict__ x,     // [T, N_IN]
                    const float* __restrict__ w0,    // [N_EXC, N_IN]
                    const float* __restrict__ tp_ws, // [T, N_IN]
                    float* __restrict__ out)         // [T, N_EXC]
{
    __shared__ __align__(16) float xs[2][N_IN];      // 16 KiB double buffer

    const int tid  = threadIdx.x;
    const int lane = tid & 63;
    const int wid  = tid >> 6;
    const int row  = blockIdx.x * 4 + wid;

    // lane l owns columns j = m*256 + l*4 + {0..3}, m = 0..7
    float w[32];
    {
        const float4* wrow = reinterpret_cast<const float4*>(w0 + (size_t)row * N_IN);
        #pragma unroll
        for (int m = 0; m < 8; ++m) {
            float4 t4 = wrow[m * 64 + lane];
            w[4*m+0] = t4.x; w[4*m+1] = t4.y; w[4*m+2] = t4.z; w[4*m+3] = t4.w;
        }
    }

    // staging: wave wid covers floats [wid*512, wid*512+512) of each row,
    // as two 16B chunks per lane (conflict-free ds_write_b128 pattern).
    const int stage_f = wid * 512 + lane * 4;
    const float4* tpb = reinterpret_cast<const float4*>(tp_ws) + lane;
    float* outp = out + row;

    // prologue: row 0 -> xs[0]; row 1 -> pr
    {
        const float* s0 = x + stage_f;
        *reinterpret_cast<float4*>(&xs[0][stage_f])       = *reinterpret_cast<const float4*>(s0);
        *reinterpret_cast<float4*>(&xs[0][stage_f + 256]) = *reinterpret_cast<const float4*>(s0 + 256);
    }
    float4 pr0, pr1;
    {
        const float* s1 = x + N_IN + stage_f;
        pr0 = *reinterpret_cast<const float4*>(s1);
        pr1 = *reinterpret_cast<const float4*>(s1 + 256);
    }
    __syncthreads();

    float v = 0.f, syn = 0.f, rho = 0.f, tpost = 0.f;

    for (int t = 0; t < T_STEPS; ++t) {
        // ---- (1) ds_read row t fragments ----
        float4 xq[8];
        {
            const float4* xl = reinterpret_cast<const float4*>(xs[t & 1]);
            #pragma unroll
            for (int m = 0; m < 8; ++m) xq[m] = xl[m * 64 + lane];
        }

        // ---- (2) ds_write row t+1 (other waves last read this buffer in
        //          step t-1, before the step-(t-1) barrier) ----
        {
            float* d = &xs[(t + 1) & 1][stage_f];
            *reinterpret_cast<float4*>(d)       = pr0;
            *reinterpret_cast<float4*>(d + 256) = pr1;
        }

        // ---- (3) one barrier: publishes row t+1; lgkm drain before
        //          s_barrier makes (1)'s reads safe vs next-step writers ----
        __syncthreads();

        // ---- (4) global-load row t+2 (consumed at step t+1's (2)) ----
        {
            int tn = t + 2; if (tn > T_STEPS - 1) tn = T_STEPS - 1;
            const float* s = x + (size_t)tn * N_IN + stage_f;
            pr0 = *reinterpret_cast<const float4*>(s);
            pr1 = *reinterpret_cast<const float4*>(s + 256);
        }

        // ---- (5) scalar LIF: spike known BEFORE the dot (v_dec uses the
        //          OLD synaptic current) ----
        const float v_dec = fmaf(0.1f, syn - v, v);
        const bool refrac = (rho > 0.f);
        const bool spike  = (v_dec > 1.0f) && !refrac;
        v   = (spike || refrac) ? 0.f : v_dec;
        rho = spike ? 5.0f : fmaxf(rho - 1.0f, 0.f);
        const float zf = spike ? 1.f : 0.f;
        tpost = fmaf(0.05f, zf - tpost, tpost);
        const float c2 = 1e-3f * tpost;
        if (lane == 0) *outp = zf;
        outp += N_EXC;

        // ---- (6) early t_pre loads on spike steps ----
        float4 tq[8];
        if (spike) {
            const float4* tq4 = tpb + (size_t)t * (N_IN / 4);
            #pragma unroll
            for (int m = 0; m < 8; ++m) tq[m] = tq4[m * 64];
        }

        // ---- (7) dot product over PRE-update w ----
        float a0 = 0.f, a1 = 0.f, a2 = 0.f, a3 = 0.f;
        #pragma unroll
        for (int m = 0; m < 8; ++m) {
            a0 = fmaf(xq[m].x, w[4*m+0], a0);
            a1 = fmaf(xq[m].y, w[4*m+1], a1);
            a2 = fmaf(xq[m].z, w[4*m+2], a2);
            a3 = fmaf(xq[m].w, w[4*m+3], a3);
        }

        // ---- (8) STDP update: 1 clamp-fma/elem non-spike ----
        if (spike) {
            #pragma unroll
            for (int m = 0; m < 8; ++m) {
                w[4*m+0] = clamp01(fmaf(1e-3f, tq[m].x, fmaf(-c2, xq[m].x, w[4*m+0])));
                w[4*m+1] = clamp01(fmaf(1e-3f, tq[m].y, fmaf(-c2, xq[m].y, w[4*m+1])));
                w[4*m+2] = clamp01(fmaf(1e-3f, tq[m].z, fmaf(-c2, xq[m].z, w[4*m+2])));
                w[4*m+3] = clamp01(fmaf(1e-3f, tq[m].w, fmaf(-c2, xq[m].w, w[4*m+3])));
            }
        } else {
            #pragma unroll
            for (int m = 0; m < 8; ++m) {
                w[4*m+0] = clamp01(fmaf(-c2, xq[m].x, w[4*m+0]));
                w[4*m+1] = clamp01(fmaf(-c2, xq[m].y, w[4*m+1]));
                w[4*m+2] = clamp01(fmaf(-c2, xq[m].z, w[4*m+2]));
                w[4*m+3] = clamp01(fmaf(-c2, xq[m].w, w[4*m+3]));
            }
        }

        // ---- (9) reduce LAST: consumed by step t+1's syn update ----
        syn = fmaf(0.8f, syn, wave_sum64((a0 + a1) + (a2 + a3)));
    }
}

extern "C" void kernel_launch(void* const* d_in, const int* in_sizes, int n_in,
                              void* d_out, int out_size, void* d_ws, size_t ws_size,
                              hipStream_t stream) {
    const float* x  = (const float*)d_in[0];   // exc_currents [128, 2048] f32
    const float* w0 = (const float*)d_in[1];   // w_exc [2048, 2048] f32
    // d_in[2] (w_inh) unused: inhibitory layer does not affect the output
    float* out = (float*)d_out;                // spikes [128, 2048] f32

    float* tp_ws = (float*)d_ws;               // 1 MiB, ws_size is ample
    tp_precompute_kernel<<<N_IN / 256, 256, 0, stream>>>(x, tp_ws);

    dim3 grid(N_EXC / 4);                      // 512 blocks, 2 blocks/CU
    dim3 block(256);                           // 4 waves = 4 neurons
    snn_exc_kernel<<<grid, block, 0, stream>>>(x, w0, tp_ws, out);
}